// Round 2
// baseline (341.586 us; speedup 1.0000x reference)
//
#include <hip/hip_runtime.h>
#include <math.h>

#define NL 45
#define START_IDX 43
#define STOP_IDX 44

__device__ __forceinline__ float wave_max64(float v) {
    v = fmaxf(v, __shfl_xor(v, 32, 64));
    v = fmaxf(v, __shfl_xor(v, 16, 64));
    v = fmaxf(v, __shfl_xor(v, 8, 64));
    v = fmaxf(v, __shfl_xor(v, 4, 64));
    v = fmaxf(v, __shfl_xor(v, 2, 64));
    v = fmaxf(v, __shfl_xor(v, 1, 64));
    return v;
}

__device__ __forceinline__ float wave_sum64(float v) {
    v += __shfl_xor(v, 32, 64);
    v += __shfl_xor(v, 16, 64);
    v += __shfl_xor(v, 8, 64);
    v += __shfl_xor(v, 4, 64);
    v += __shfl_xor(v, 2, 64);
    v += __shfl_xor(v, 1, 64);
    return v;
}

// One wave (64 lanes) per batch element; lane i (<45) owns label i.
// Exp-domain CRF forward:  q_i = exp(alpha_i - M),  recurrence
//   q'_i = exp(logit[t][i]) * sum_j exp(trans[i][j]) * q_j
// E-row (exp of transitions) held in 45 VGPRs per lane; q[j] broadcast via
// v_readlane -> SGPR fma operand. No LDS, no per-step log/max-reduce.
// Scale tracked as an exact power-of-two shift count (renorm by 2^±96 when a
// 2-instr ballot fires, every ~20-30 steps).
__global__ __launch_bounds__(64, 1) void crf_fwd_kernel(
        const float* __restrict__ logits,
        const int* __restrict__ lens,
        const float* __restrict__ trans,
        float* __restrict__ out,
        int S) {
    const int b = blockIdx.x;
    const int lane = threadIdx.x;
    const bool real = lane < NL;
    const int rl = real ? lane : 0;   // clamped label index for safe addresses

    // --- one-time: E row (exp of transitions), stop-transition score ---
    float Erow[NL];
#pragma unroll
    for (int j = 0; j < NL; ++j) {
        float tv = trans[rl * NL + j];
        Erow[j] = real ? __expf(tv) : 0.0f;   // pad lanes: zero row -> S=0 -> q stays 0
    }
    const float tstop = trans[STOP_IDX * NL + rl];

    const int len = lens[b];

    // --- init: reference alpha0 = -1e4 (exp underflows to exactly 0 in fp32),
    //     0 at START. q = exp(alpha0 - 0). Pads: q = 0 forever. ---
    float q = (real && lane == START_IDX) ? 1.0f : 0.0f;
    int shift96 = 0;   // alpha = log(q) + shift96 * 96 * ln2

    // --- logits pointer for this batch/lane; depth-4 prefetch pipeline ---
    const float* lp = logits + (size_t)b * (size_t)S * NL + rl;
    const int tmax = S - 1;
    float f0 = lp[(size_t)((0 < tmax) ? 0 : tmax) * NL];
    float f1 = lp[(size_t)((1 < tmax) ? 1 : tmax) * NL];
    float f2 = lp[(size_t)((2 < tmax) ? 2 : tmax) * NL];
    float f3 = lp[(size_t)((3 < tmax) ? 3 : tmax) * NL];

    for (int t = 0; t < len; ++t) {
        // prefetch t+4 (clamped address, always in-bounds)
        int tn = t + 4; tn = (tn < tmax) ? tn : tmax;
        const float fn = lp[(size_t)tn * NL];

        // emission factor (input prefetched 4 steps ago -> off critical path)
        const float el = __expf(f0);

        // --- S_i = sum_j E[i][j] * q[j]; q[j] via readlane -> SGPR fma operand ---
        float acc0 = 0.0f, acc1 = 0.0f, acc2 = 0.0f, acc3 = 0.0f;
#pragma unroll
        for (int j = 0; j < NL; ++j) {
            const float qj = __uint_as_float(
                __builtin_amdgcn_readlane(__float_as_uint(q), j));
            switch (j & 3) {
                case 0: acc0 = fmaf(Erow[j], qj, acc0); break;
                case 1: acc1 = fmaf(Erow[j], qj, acc1); break;
                case 2: acc2 = fmaf(Erow[j], qj, acc2); break;
                default: acc3 = fmaf(Erow[j], qj, acc3); break;
            }
        }
        const float Ssum = (acc0 + acc1) + (acc2 + acc3);

        q = el * Ssum;   // pads: 0 * anything = 0

        // --- renorm by exact powers of two (rare; wave-uniform branches) ---
        // Overflow headroom: qmax <= 1e30 here; one step's worst growth for
        // N(0,1) data is < 5e4 -> < 5e34 << 3.4e38. All-underflow impossible:
        // qmax >= 1e-30 guaranteed -> q'max >= ~1e-34 > 0.
        if (__any(q > 1e30f)) {
            q *= 0x1p-96f; ++shift96;
        } else if (!__any(q > 1e-30f)) {
            q *= 0x1p96f; --shift96;
        }

        // rotate prefetch pipeline
        f0 = f1; f1 = f2; f2 = f3; f3 = fn;
    }

    // --- epilogue: norm = M + LSE_i(log(q_i) + trans[STOP][i]) ---
    const float a = __logf(q) + tstop;       // q=0 (pads) -> -inf
    const float mm = wave_max64(a);
    const float e = __expf(a - mm);          // -inf - mm -> 0
    const float ssum = wave_sum64(e);
    if (lane == 0) {
        const float M = (float)(shift96 * 96) * 0.69314718055994531f;
        out[b] = M + mm + __logf(ssum);
    }
}

extern "C" void kernel_launch(void* const* d_in, const int* in_sizes, int n_in,
                              void* d_out, int out_size, void* d_ws, size_t ws_size,
                              hipStream_t stream) {
    const float* logits = (const float*)d_in[0];
    const int* lens = (const int*)d_in[1];
    const float* trans = (const float*)d_in[2];
    float* out = (float*)d_out;

    const int B = in_sizes[1];                       // 1024
    const int S = in_sizes[0] / (B * NL);            // 512

    crf_fwd_kernel<<<B, 64, 0, stream>>>(logits, lens, trans, out, S);
}

// Round 4
// 340.460 us; speedup vs baseline: 1.0033x; 1.0033x over previous
//
#include <hip/hip_runtime.h>
#include <math.h>

#define NL 45
#define START_IDX 43
#define STOP_IDX 44

#define FOR45(F) \
  F(0) F(1) F(2) F(3) F(4) F(5) F(6) F(7) F(8) F(9) \
  F(10) F(11) F(12) F(13) F(14) F(15) F(16) F(17) F(18) F(19) \
  F(20) F(21) F(22) F(23) F(24) F(25) F(26) F(27) F(28) F(29) \
  F(30) F(31) F(32) F(33) F(34) F(35) F(36) F(37) F(38) F(39) \
  F(40) F(41) F(42) F(43) F(44)

__device__ __forceinline__ float wave_max64(float v) {
    v = fmaxf(v, __shfl_xor(v, 32, 64));
    v = fmaxf(v, __shfl_xor(v, 16, 64));
    v = fmaxf(v, __shfl_xor(v, 8, 64));
    v = fmaxf(v, __shfl_xor(v, 4, 64));
    v = fmaxf(v, __shfl_xor(v, 2, 64));
    v = fmaxf(v, __shfl_xor(v, 1, 64));
    return v;
}

__device__ __forceinline__ float wave_sum64(float v) {
    v += __shfl_xor(v, 32, 64);
    v += __shfl_xor(v, 16, 64);
    v += __shfl_xor(v, 8, 64);
    v += __shfl_xor(v, 4, 64);
    v += __shfl_xor(v, 2, 64);
    v += __shfl_xor(v, 1, 64);
    return v;
}

// One wave (64 lanes) per batch element; lane i (<45) owns label i.
// Exp-domain CRF forward:  q_i = exp(alpha_i - M),  recurrence
//   q'_i = exp(logit[t][i]) * sum_j exp(trans[i][j]) * q_j
// E row held in 45 *named scalar* VGPRs (r2's array version was demoted to
// scratch: VGPR_Count=36, WRITE_SIZE=40MB of spill traffic). q[j] broadcast
// via v_readlane -> SGPR fma operand: no LDS, no per-step log/max-reduce.
// Scale tracked as exact power-of-two shifts (rare 2-instr ballot).
__global__ __launch_bounds__(64, 1) void crf_fwd_kernel(
        const float* __restrict__ logits,
        const int* __restrict__ lens,
        const float* __restrict__ trans,
        float* __restrict__ out,
        int S) {
    const int b = blockIdx.x;
    const int lane = threadIdx.x;
    const bool real = lane < NL;
    const int rl = real ? lane : 0;   // clamped label index for safe addresses

    // --- one-time: E row as 45 named scalars (cannot be demoted to scratch) ---
#define E_DECL(J) float e##J = real ? __expf(trans[rl * NL + (J)]) : 0.0f;
    FOR45(E_DECL)
#undef E_DECL
    const float tstop = trans[STOP_IDX * NL + rl];

    const int len = lens[b];

    // --- init: alpha0 = -1e4 (exp underflows to exactly 0), 0 at START ---
    float q = (real && lane == START_IDX) ? 1.0f : 0.0f;
    int shift96 = 0;   // alpha = log(q) + shift96 * 96 * ln2

    // --- logits pointer for this batch/lane; depth-4 prefetch ring ---
    const float* lp = logits + (size_t)b * (size_t)S * NL + rl;
    const int tmax = S - 1;
    float f0 = lp[(size_t)((0 < tmax) ? 0 : tmax) * NL];
    float f1 = lp[(size_t)((1 < tmax) ? 1 : tmax) * NL];
    float f2 = lp[(size_t)((2 < tmax) ? 2 : tmax) * NL];
    float f3 = lp[(size_t)((3 < tmax) ? 3 : tmax) * NL];

#pragma unroll 4
    for (int t = 0; t < len; ++t) {
        // prefetch t+4 (clamped address, always in-bounds)
        int tn = t + 4; tn = (tn < tmax) ? tn : tmax;
        const float fn = lp[(size_t)tn * NL];

        // emission factor (operand prefetched 4 steps ago -> off critical path)
        const float el = __expf(f0);

        // --- S_i = sum_j e_j * q[j]; q[j] via readlane -> SGPR fma operand ---
        float acc[4] = {0.0f, 0.0f, 0.0f, 0.0f};
#define MAC(J) { \
        const float q_##J = __uint_as_float( \
            __builtin_amdgcn_readlane(__float_as_uint(q), (J))); \
        acc[(J) & 3] = fmaf(e##J, q_##J, acc[(J) & 3]); }
        FOR45(MAC)
#undef MAC
        const float Ssum = (acc[0] + acc[1]) + (acc[2] + acc[3]);

        q = el * Ssum;   // pad lanes: 0 * anything = 0

        // --- renorm by exact powers of two (rare; wave-uniform branches) ---
        // qmax <= 1e30 entering a step; worst one-step growth < 5e4 -> no
        // overflow. All-underflow impossible: qmax > 1e-30 maintained below.
        if (__any(q > 1e30f)) {
            q *= 0x1p-96f; ++shift96;
        } else if (!__any(q > 1e-30f)) {
            q *= 0x1p96f; --shift96;
        }

        // rotate prefetch ring (renamed away under unroll-4)
        f0 = f1; f1 = f2; f2 = f3; f3 = fn;
    }

    // --- epilogue: norm = M + LSE_i(log(q_i) + trans[STOP][i]) ---
    const float a = __logf(q) + tstop;       // q=0 (pads) -> -inf
    const float mm = wave_max64(a);
    const float e = __expf(a - mm);          // exp(-inf - mm) = 0
    const float ssum = wave_sum64(e);
    if (lane == 0) {
        const float M = (float)(shift96 * 96) * 0.69314718055994531f;
        out[b] = M + mm + __logf(ssum);
    }
}

extern "C" void kernel_launch(void* const* d_in, const int* in_sizes, int n_in,
                              void* d_out, int out_size, void* d_ws, size_t ws_size,
                              hipStream_t stream) {
    const float* logits = (const float*)d_in[0];
    const int* lens = (const int*)d_in[1];
    const float* trans = (const float*)d_in[2];
    float* out = (float*)d_out;

    const int B = in_sizes[1];                       // 1024
    const int S = in_sizes[0] / (B * NL);            // 512

    crf_fwd_kernel<<<B, 64, 0, stream>>>(logits, lens, trans, out, S);
}

// Round 5
// 334.290 us; speedup vs baseline: 1.0218x; 1.0185x over previous
//
#include <hip/hip_runtime.h>
#include <math.h>

#define NL 45
#define START_IDX 43
#define STOP_IDX 44

#define FOR45(F) \
  F(0) F(1) F(2) F(3) F(4) F(5) F(6) F(7) F(8) F(9) \
  F(10) F(11) F(12) F(13) F(14) F(15) F(16) F(17) F(18) F(19) \
  F(20) F(21) F(22) F(23) F(24) F(25) F(26) F(27) F(28) F(29) \
  F(30) F(31) F(32) F(33) F(34) F(35) F(36) F(37) F(38) F(39) \
  F(40) F(41) F(42) F(43) F(44)

__device__ __forceinline__ float wave_max64(float v) {
    v = fmaxf(v, __shfl_xor(v, 32, 64));
    v = fmaxf(v, __shfl_xor(v, 16, 64));
    v = fmaxf(v, __shfl_xor(v, 8, 64));
    v = fmaxf(v, __shfl_xor(v, 4, 64));
    v = fmaxf(v, __shfl_xor(v, 2, 64));
    v = fmaxf(v, __shfl_xor(v, 1, 64));
    return v;
}

__device__ __forceinline__ float wave_sum64(float v) {
    v += __shfl_xor(v, 32, 64);
    v += __shfl_xor(v, 16, 64);
    v += __shfl_xor(v, 8, 64);
    v += __shfl_xor(v, 4, 64);
    v += __shfl_xor(v, 2, 64);
    v += __shfl_xor(v, 1, 64);
    return v;
}

// One wave (64 lanes) per batch element; lane i (<45) owns label i.
// Exp-domain CRF forward:  q_i = exp(alpha_i - M),  recurrence
//   q'_i = exp(logit[t][i]) * sum_j exp(trans[i][j]) * q_j
//
// r2/r3 lesson: at 1 wave/SIMD (grid=1024), kernel time == serial critical
// path of the len=512 wave (measured 1111 cyc/step). The allocator chose a
// 36-VGPR allocation and spilled/remat'd the 45 E-values in-loop (41 MB
// scratch writes), putting ~200-cyc reload latency on the serial chain.
// Fixes: (a) amdgpu_waves_per_eu(1,1) -- regalloc may use the full 512-VGPR
// budget, spilling buys nothing; (b) opaque-asm pin of all 45 E scalars --
// defeats remat-by-reload. Goal: zero memory ops in the loop except the
// depth-4 logits prefetch.
__global__ __attribute__((amdgpu_flat_work_group_size(64, 64),
                          amdgpu_waves_per_eu(1, 1)))
void crf_fwd_kernel(
        const float* __restrict__ logits,
        const int* __restrict__ lens,
        const float* __restrict__ trans,
        float* __restrict__ out,
        int S) {
    const int b = blockIdx.x;
    const int lane = threadIdx.x;
    const bool real = lane < NL;
    const int rl = real ? lane : 0;   // clamped label index for safe addresses

    // --- one-time: E row as 45 named scalars ---
#define E_DECL(J) float e##J = real ? __expf(trans[rl * NL + (J)]) : 0.0f;
    FOR45(E_DECL)
#undef E_DECL

    // Pin E in VGPRs: opaque defs the compiler can neither remat nor sink.
    // (Split: inline asm is limited to ~30 operands.)
    asm volatile("" : "+v"(e0), "+v"(e1), "+v"(e2), "+v"(e3), "+v"(e4),
                      "+v"(e5), "+v"(e6), "+v"(e7), "+v"(e8), "+v"(e9),
                      "+v"(e10), "+v"(e11), "+v"(e12), "+v"(e13), "+v"(e14),
                      "+v"(e15), "+v"(e16), "+v"(e17), "+v"(e18), "+v"(e19),
                      "+v"(e20), "+v"(e21), "+v"(e22));
    asm volatile("" : "+v"(e23), "+v"(e24), "+v"(e25), "+v"(e26), "+v"(e27),
                      "+v"(e28), "+v"(e29), "+v"(e30), "+v"(e31), "+v"(e32),
                      "+v"(e33), "+v"(e34), "+v"(e35), "+v"(e36), "+v"(e37),
                      "+v"(e38), "+v"(e39), "+v"(e40), "+v"(e41), "+v"(e42),
                      "+v"(e43), "+v"(e44));

    const float tstop = trans[STOP_IDX * NL + rl];

    const int len = lens[b];

    // --- init: alpha0 = -1e4 (exp underflows to exactly 0), 0 at START ---
    float q = (real && lane == START_IDX) ? 1.0f : 0.0f;
    int shift96 = 0;   // alpha = log(q) + shift96 * 96 * ln2

    // --- logits pointer for this batch/lane; depth-4 prefetch ring ---
    const float* lp = logits + (size_t)b * (size_t)S * NL + rl;
    const int tmax = S - 1;
    float f0 = lp[(size_t)((0 < tmax) ? 0 : tmax) * NL];
    float f1 = lp[(size_t)((1 < tmax) ? 1 : tmax) * NL];
    float f2 = lp[(size_t)((2 < tmax) ? 2 : tmax) * NL];
    float f3 = lp[(size_t)((3 < tmax) ? 3 : tmax) * NL];

#pragma unroll 4
    for (int t = 0; t < len; ++t) {
        // prefetch t+4 (clamped address, always in-bounds)
        int tn = t + 4; tn = (tn < tmax) ? tn : tmax;
        const float fn = lp[(size_t)tn * NL];

        // emission factor (operand prefetched 4 steps ago -> off critical path)
        const float el = __expf(f0);

        // --- S_i = sum_j e_j * q[j]; q[j] via readlane -> SGPR fma operand ---
        float acc[4] = {0.0f, 0.0f, 0.0f, 0.0f};
#define MAC(J) { \
        const float q_##J = __uint_as_float( \
            __builtin_amdgcn_readlane(__float_as_uint(q), (J))); \
        acc[(J) & 3] = fmaf(e##J, q_##J, acc[(J) & 3]); }
        FOR45(MAC)
#undef MAC
        const float Ssum = (acc[0] + acc[1]) + (acc[2] + acc[3]);

        q = el * Ssum;   // pad lanes: 0 * anything = 0

        // --- renorm by exact powers of two (rare; wave-uniform branches) ---
        // qmax <= 1e30 entering a step; worst one-step growth < 5e4 -> no
        // overflow. All-underflow impossible: qmax > 1e-30 maintained below.
        if (__any(q > 1e30f)) {
            q *= 0x1p-96f; ++shift96;
        } else if (!__any(q > 1e-30f)) {
            q *= 0x1p96f; --shift96;
        }

        // rotate prefetch ring (renamed away under unroll-4)
        f0 = f1; f1 = f2; f2 = f3; f3 = fn;
    }

    // --- epilogue: norm = M + LSE_i(log(q_i) + trans[STOP][i]) ---
    const float a = __logf(q) + tstop;       // q=0 (pads) -> -inf
    const float mm = wave_max64(a);
    const float e = __expf(a - mm);          // exp(-inf - mm) = 0
    const float ssum = wave_sum64(e);
    if (lane == 0) {
        const float M = (float)(shift96 * 96) * 0.69314718055994531f;
        out[b] = M + mm + __logf(ssum);
    }
}

extern "C" void kernel_launch(void* const* d_in, const int* in_sizes, int n_in,
                              void* d_out, int out_size, void* d_ws, size_t ws_size,
                              hipStream_t stream) {
    const float* logits = (const float*)d_in[0];
    const int* lens = (const int*)d_in[1];
    const float* trans = (const float*)d_in[2];
    float* out = (float*)d_out;

    const int B = in_sizes[1];                       // 1024
    const int S = in_sizes[0] / (B * NL);            // 512

    crf_fwd_kernel<<<B, 64, 0, stream>>>(logits, lens, trans, out, S);
}

// Round 7
// 234.192 us; speedup vs baseline: 1.4586x; 1.4274x over previous
//
#include <hip/hip_runtime.h>
#include <math.h>

#define NL 45
#define START_IDX 43
#define STOP_IDX 44

#define FOR45(F) \
  F(0) F(1) F(2) F(3) F(4) F(5) F(6) F(7) F(8) F(9) \
  F(10) F(11) F(12) F(13) F(14) F(15) F(16) F(17) F(18) F(19) \
  F(20) F(21) F(22) F(23) F(24) F(25) F(26) F(27) F(28) F(29) \
  F(30) F(31) F(32) F(33) F(34) F(35) F(36) F(37) F(38) F(39) \
  F(40) F(41) F(42) F(43) F(44)

__device__ __forceinline__ float wave_max64(float v) {
    v = fmaxf(v, __shfl_xor(v, 32, 64));
    v = fmaxf(v, __shfl_xor(v, 16, 64));
    v = fmaxf(v, __shfl_xor(v, 8, 64));
    v = fmaxf(v, __shfl_xor(v, 4, 64));
    v = fmaxf(v, __shfl_xor(v, 2, 64));
    v = fmaxf(v, __shfl_xor(v, 1, 64));
    return v;
}

__device__ __forceinline__ float wave_sum64(float v) {
    v += __shfl_xor(v, 32, 64);
    v += __shfl_xor(v, 16, 64);
    v += __shfl_xor(v, 8, 64);
    v += __shfl_xor(v, 4, 64);
    v += __shfl_xor(v, 2, 64);
    v += __shfl_xor(v, 1, 64);
    return v;
}

// One wave per batch element; lane i (<45) owns label i. Exp-domain CRF:
//   q'_i = exp(logit[t][i]) * sum_j exp(trans[i][j]) * q_j
// r5 lesson: VGPR 36->132 (E resident) changed NOTHING (231us, VALUBusy 15%)
// -> stall is not spills. ~945 stall cyc/step suspected from readlane->fma
// SGPR hazards + per-step votes. This version: (a) all 45 readlanes batched
// before all 45 fmas (sched_barrier(0) fence) -> hazard distance >= 45;
// (b) no votes: unconditional exact renorm (frexp/ldexp, power-of-2) every
// 4 steps; (c) prefetch ring 2 chunks (8 steps) deep.
__global__ __attribute__((amdgpu_flat_work_group_size(64, 64),
                          amdgpu_waves_per_eu(1, 1)))
void crf_fwd_kernel(
        const float* __restrict__ logits,
        const int* __restrict__ lens,
        const float* __restrict__ trans,
        float* __restrict__ out,
        int S) {
    const int b = blockIdx.x;
    const int lane = threadIdx.x;
    const bool real = lane < NL;
    const int rl = real ? lane : 0;   // clamped label index for safe addresses

    // --- one-time: E row as 45 named scalars, pinned in VGPRs ---
#define E_DECL(J) float e##J = real ? __expf(trans[rl * NL + (J)]) : 0.0f;
    FOR45(E_DECL)
#undef E_DECL
    asm volatile("" : "+v"(e0), "+v"(e1), "+v"(e2), "+v"(e3), "+v"(e4),
                      "+v"(e5), "+v"(e6), "+v"(e7), "+v"(e8), "+v"(e9),
                      "+v"(e10), "+v"(e11), "+v"(e12), "+v"(e13), "+v"(e14),
                      "+v"(e15), "+v"(e16), "+v"(e17), "+v"(e18), "+v"(e19),
                      "+v"(e20), "+v"(e21), "+v"(e22));
    asm volatile("" : "+v"(e23), "+v"(e24), "+v"(e25), "+v"(e26), "+v"(e27),
                      "+v"(e28), "+v"(e29), "+v"(e30), "+v"(e31), "+v"(e32),
                      "+v"(e33), "+v"(e34), "+v"(e35), "+v"(e36), "+v"(e37),
                      "+v"(e38), "+v"(e39), "+v"(e40), "+v"(e41), "+v"(e42),
                      "+v"(e43), "+v"(e44));

    const float tstop = trans[STOP_IDX * NL + rl];
    const int len = lens[b];

    // --- init: alpha0 = -1e4 (exp underflows to exactly 0), 0 at START ---
    float q = (real && lane == START_IDX) ? 1.0f : 0.0f;
    int esum = 0;   // alpha = log(q) + esum * ln2  (exact power-of-2 ledger)

    const float* lp = logits + (size_t)b * (size_t)S * NL + rl;
    const int tmax = S - 1;

#define LD(T) lp[(size_t)(((T) < tmax) ? (T) : tmax) * NL]
    // prefetch pipeline: f = current chunk, p = next, n = issuing (2 ahead)
    float f0 = LD(0), f1 = LD(1), f2 = LD(2), f3 = LD(3);
    float p0 = LD(4), p1 = LD(5), p2 = LD(6), p3 = LD(7);

#define RDL(J) const float qb##J = __uint_as_float( \
        __builtin_amdgcn_readlane(__float_as_uint(q), (J)));
#define MACJ(J) acc[(J) & 3] = fmaf(e##J, qb##J, acc[(J) & 3]);
    // One step: batched readlanes -> fence -> batched fmas -> uniform select.
#define STEP(K) { \
        const float el = __expf(f##K); \
        FOR45(RDL) \
        __builtin_amdgcn_sched_barrier(0); \
        float acc[4] = {0.0f, 0.0f, 0.0f, 0.0f}; \
        FOR45(MACJ) \
        const float qn = el * ((acc[0] + acc[1]) + (acc[2] + acc[3])); \
        q = (t0 + (K) < len) ? qn : q; \
    }

    for (int t0 = 0; t0 < len; t0 += 4) {
        // issue loads for chunk t0+8..t0+11 (2 chunks ahead, clamped)
        const float n0 = LD(t0 + 8), n1 = LD(t0 + 9);
        const float n2 = LD(t0 + 10), n3 = LD(t0 + 11);

        STEP(0) STEP(1) STEP(2) STEP(3)

        // --- exact renorm every 4 steps (no votes, no branches) ---
        // Worst-case chunk growth < 2^75 from qmax<1 -> no overflow possible.
        const float mq = wave_max64(q);          // wave-uniform, > 0 always
        int ex; (void)frexpf(mq, &ex);           // mq = mant * 2^ex
        q = ldexpf(q, -ex);                      // exact scaling
        esum += ex;

        // rotate prefetch pipeline (renamed away)
        f0 = p0; f1 = p1; f2 = p2; f3 = p3;
        p0 = n0; p1 = n1; p2 = n2; p3 = n3;
    }
#undef STEP
#undef MACJ
#undef RDL
#undef LD

    // --- epilogue: norm = esum*ln2 + LSE_i(log(q_i) + trans[STOP][i]) ---
    const float a = __logf(q) + tstop;       // q=0 (pads) -> -inf
    const float mm = wave_max64(a);
    const float e = __expf(a - mm);          // exp(-inf - mm) = 0
    const float ssum = wave_sum64(e);
    if (lane == 0) {
        const float M = (float)esum * 0.69314718055994531f;
        out[b] = M + mm + __logf(ssum);
    }
}

extern "C" void kernel_launch(void* const* d_in, const int* in_sizes, int n_in,
                              void* d_out, int out_size, void* d_ws, size_t ws_size,
                              hipStream_t stream) {
    const float* logits = (const float*)d_in[0];
    const int* lens = (const int*)d_in[1];
    const float* trans = (const float*)d_in[2];
    float* out = (float*)d_out;

    const int B = in_sizes[1];                       // 1024
    const int S = in_sizes[0] / (B * NL);            // 512

    crf_fwd_kernel<<<B, 64, 0, stream>>>(logits, lens, trans, out, S);
}